// Round 1
// baseline (522.104 us; speedup 1.0000x reference)
//
#include <hip/hip_runtime.h>
#include <hip/hip_bf16.h>

// ---------------------------------------------------------------------------
// Fully-fused SwinV2 window attention, one workgroup per window.
//   B=4096 windows, N=64 tokens, DIM=256, H=8 heads, HD=32, NW=1024 masks.
// All GEMMs: v_mfma_f32_16x16x32_bf16, f32 accumulate.
// Fragment layout assumption (gfx950 2xK):
//   A: lane l holds A[l&15][k], k = 4*(l>>4)+j (j=0..3), 16+4*(l>>4)+(j-4) (j=4..7)
//   B: lane l holds B[k][l&15], same k pattern
//   C/D: col = l&15, row = 4*(l>>4)+reg            (HW-verified per guide)
// LDS bf16 tiles are stored in "packed-32" order so every fragment is ONE
// 16-byte ds_read_b128: within each 32-col block, pos = lg*8 + e  <->
// k = 4*lg+e (e<4) | 16+4*lg+(e-4).
// ---------------------------------------------------------------------------

typedef __attribute__((ext_vector_type(4))) float f32x4;
typedef __attribute__((ext_vector_type(8))) short bf16x8;   // 8 bf16 in 4 VGPRs
typedef __attribute__((ext_vector_type(4))) unsigned int u32x4;

#define MFMA16(a, b, c) __builtin_amdgcn_mfma_f32_16x16x32_bf16((a), (b), (c), 0, 0, 0)

union FragAB {
  bf16x8 v;
  ushort u[8];
  u32x4  q4;
};

__device__ __forceinline__ ushort f2b(float f) {
  union { float f; unsigned int u; } cv; cv.f = f;
  unsigned int u = cv.u;
  return (ushort)((u + 0x7fffu + ((u >> 16) & 1u)) >> 16);   // RNE
}

__device__ __forceinline__ bf16x8 ldfrag(const ushort* p) {
  FragAB f;
  f.q4 = *(const u32x4*)p;
  return f.v;
}

__device__ __forceinline__ f32x4 fzero() {
  f32x4 z = {0.0f, 0.0f, 0.0f, 0.0f};
  return z;
}

// ---------------------------------------------------------------------------
// Prep: bf16-convert + MFMA-fragment-repack weights; build biasT[h][m][n];
// per-head logit scales.  Packed weight index: o*256 + kg*32 + lg*8 + e.
// ---------------------------------------------------------------------------
__global__ void prep_kernel(const float* __restrict__ qw, const float* __restrict__ kvw,
                            const float* __restrict__ pw, const float* __restrict__ rpb,
                            const float* __restrict__ lsc,
                            ushort* __restrict__ qwb, ushort* __restrict__ kvwb,
                            ushort* __restrict__ pwb, float* __restrict__ biasT,
                            float* __restrict__ scale) {
  int t = blockIdx.x * blockDim.x + threadIdx.x;
  int stride = gridDim.x * blockDim.x;
  for (int i = t; i < 256 * 256; i += stride) {
    int o = i >> 8, rem = i & 255;
    int kg = rem >> 5, r2 = rem & 31, lg = r2 >> 3, e = r2 & 7;
    int k = (kg << 5) + (lg << 2) + (e < 4 ? e : e + 12);    // 16+4lg+(e-4)
    qwb[i] = f2b(qw[(o << 8) + k]);
    pwb[i] = f2b(pw[(o << 8) + k]);
  }
  for (int i = t; i < 512 * 256; i += stride) {
    int o = i >> 8, rem = i & 255;
    int kg = rem >> 5, r2 = rem & 31, lg = r2 >> 3, e = r2 & 7;
    int k = (kg << 5) + (lg << 2) + (e < 4 ? e : e + 12);
    kvwb[i] = f2b(kvw[(o << 8) + k]);
  }
  // biasT[h][m][n] = bias[h][n][m] = rpb_table[RPI[n][m]][h]
  for (int i = t; i < 8 * 64 * 64; i += stride) {
    int h = i >> 12, m = (i >> 6) & 63, n = i & 63;
    int idx = ((n >> 3) - (m >> 3) + 7) * 15 + ((n & 7) - (m & 7) + 7);
    biasT[i] = rpb[idx * 8 + h];
  }
  if (t < 8) scale[t] = __expf(fminf(lsc[t], 4.6051701859880914f));  // log(100)
}

// ---------------------------------------------------------------------------
// Main fused kernel: 512 threads = 8 waves; wave w owns head w / col block w.
// ---------------------------------------------------------------------------
__global__ __launch_bounds__(512, 2)
void wattn_fused(const float* __restrict__ xg, const float* __restrict__ cg,
                 const float* __restrict__ maskg,
                 const float* __restrict__ qb, const float* __restrict__ kvb,
                 const float* __restrict__ pb,
                 const ushort* __restrict__ qwb, const ushort* __restrict__ kvwb,
                 const ushort* __restrict__ pwb,
                 const float* __restrict__ biasT, const float* __restrict__ scaleg,
                 float* __restrict__ outg) {
  // LDS: 3*33792 + 36864 + 16640 = 154880 B  (<160 KiB, 1 block/CU)
  __shared__ ushort xs[64][264];    // x -> c -> attention-output (packed cols)
  __shared__ ushort qs[64][264];    // normalized q  (packed cols)
  __shared__ ushort ks[64][264];    // normalized k  (packed cols)
  __shared__ ushort vts[256][72];   // v transposed: [h*32+d][m packed]
  __shared__ float  ms[64][65];     // maskT[m][n]

  const int b    = blockIdx.x;
  const int wid  = b & 1023;          // window id (b = batch*1024 + w)
  const int tid  = threadIdx.x;
  const int w    = tid >> 6;          // wave / head 0..7
  const int lane = tid & 63;
  const int lg   = lane >> 4;         // 0..3
  const int lc   = lane & 15;         // 0..15
  const int c0   = w << 5;            // this wave's 32-col block base

  // ---- Phase A: stage x (f32 -> packed bf16 LDS) + mask transpose ----
  {
    const float4* src = (const float4*)(xg + (size_t)b * 16384);
#pragma unroll
    for (int it = 0; it < 8; ++it) {
      int i = tid + it * 512;
      float4 v = src[i];
      int row = i >> 6;
      int col = (i & 63) << 2;
      ushort* p = &xs[row][(col & ~31) + (((col & 15) >> 2) << 3) + ((col & 16) ? 4 : 0)];
      p[0] = f2b(v.x); p[1] = f2b(v.y); p[2] = f2b(v.z); p[3] = f2b(v.w);
    }
    const float* mp = maskg + (size_t)wid * 4096;
#pragma unroll
    for (int it = 0; it < 8; ++it) {
      int i = tid + it * 512;
      ms[i & 63][i >> 6] = mp[i];     // ms[m][n] = mask[w][n][m]
    }
  }
  __syncthreads();

  // ---- Phase B: Q = x @ qw^T + qb, per-head L2 norm -> qs ----
  {
    f32x4 acc[4][2];
#pragma unroll
    for (int mt = 0; mt < 4; ++mt)
#pragma unroll
      for (int nt = 0; nt < 2; ++nt) acc[mt][nt] = fzero();
#pragma unroll
    for (int kg = 0; kg < 8; ++kg) {
      bf16x8 a[4], bb[2];
#pragma unroll
      for (int mt = 0; mt < 4; ++mt)
        a[mt] = ldfrag(&xs[mt * 16 + lc][(kg << 5) + (lg << 3)]);
#pragma unroll
      for (int nt = 0; nt < 2; ++nt)
        bb[nt] = ldfrag(qwb + ((c0 + nt * 16 + lc) << 8) + (kg << 5) + (lg << 3));
#pragma unroll
      for (int mt = 0; mt < 4; ++mt)
#pragma unroll
        for (int nt = 0; nt < 2; ++nt)
          acc[mt][nt] = MFMA16(a[mt], bb[nt], acc[mt][nt]);
    }
    float bias0 = qb[c0 + lc], bias1 = qb[c0 + 16 + lc];
    const int cp0 = c0 + ((lc >> 2) << 3) + (lc & 3);
#pragma unroll
    for (int mt = 0; mt < 4; ++mt) {
#pragma unroll
      for (int reg = 0; reg < 4; ++reg) {
        float v0 = acc[mt][0][reg] + bias0;
        float v1 = acc[mt][1][reg] + bias1;
        float ss = v0 * v0 + v1 * v1;
        ss += __shfl_xor(ss, 1);
        ss += __shfl_xor(ss, 2);
        ss += __shfl_xor(ss, 4);
        ss += __shfl_xor(ss, 8);
        float inv = 1.0f / fmaxf(sqrtf(ss), 1e-12f);
        int row = mt * 16 + (lg << 2) + reg;
        qs[row][cp0]     = f2b(v0 * inv);
        qs[row][cp0 + 4] = f2b(v1 * inv);
      }
    }
  }
  __syncthreads();

  // ---- Phase C: stage c over x's buffer ----
  {
    const float4* src = (const float4*)(cg + (size_t)b * 16384);
#pragma unroll
    for (int it = 0; it < 8; ++it) {
      int i = tid + it * 512;
      float4 v = src[i];
      int row = i >> 6;
      int col = (i & 63) << 2;
      ushort* p = &xs[row][(col & ~31) + (((col & 15) >> 2) << 3) + ((col & 16) ? 4 : 0)];
      p[0] = f2b(v.x); p[1] = f2b(v.y); p[2] = f2b(v.z); p[3] = f2b(v.w);
    }
  }
  __syncthreads();

  // ---- Phase D: KV GEMM. pass0: K (norm -> ks); pass1: V (-> vts transposed) ----
  {
#pragma unroll
    for (int pass = 0; pass < 2; ++pass) {
      const int o0 = (pass << 8) + c0;
      f32x4 acc[4][2];
#pragma unroll
      for (int mt = 0; mt < 4; ++mt)
#pragma unroll
        for (int nt = 0; nt < 2; ++nt) acc[mt][nt] = fzero();
#pragma unroll
      for (int kg = 0; kg < 8; ++kg) {
        bf16x8 a[4], bb[2];
#pragma unroll
        for (int mt = 0; mt < 4; ++mt)
          a[mt] = ldfrag(&xs[mt * 16 + lc][(kg << 5) + (lg << 3)]);
#pragma unroll
        for (int nt = 0; nt < 2; ++nt)
          bb[nt] = ldfrag(kvwb + ((o0 + nt * 16 + lc) << 8) + (kg << 5) + (lg << 3));
#pragma unroll
        for (int mt = 0; mt < 4; ++mt)
#pragma unroll
          for (int nt = 0; nt < 2; ++nt)
            acc[mt][nt] = MFMA16(a[mt], bb[nt], acc[mt][nt]);
      }
      float bias0 = kvb[o0 + lc], bias1 = kvb[o0 + 16 + lc];
      if (pass == 0) {
        const int cp0 = c0 + ((lc >> 2) << 3) + (lc & 3);
#pragma unroll
        for (int mt = 0; mt < 4; ++mt) {
#pragma unroll
          for (int reg = 0; reg < 4; ++reg) {
            float v0 = acc[mt][0][reg] + bias0;
            float v1 = acc[mt][1][reg] + bias1;
            float ss = v0 * v0 + v1 * v1;
            ss += __shfl_xor(ss, 1);
            ss += __shfl_xor(ss, 2);
            ss += __shfl_xor(ss, 4);
            ss += __shfl_xor(ss, 8);
            float inv = 1.0f / fmaxf(sqrtf(ss), 1e-12f);
            int row = mt * 16 + (lg << 2) + reg;
            ks[row][cp0]     = f2b(v0 * inv);
            ks[row][cp0 + 4] = f2b(v1 * inv);
          }
        }
      } else {
#pragma unroll
        for (int mt = 0; mt < 4; ++mt) {
#pragma unroll
          for (int reg = 0; reg < 4; ++reg) {
            // token m -> packed col; d = nt*16+lc -> vts row c0 + nt*16 + lc
            int mpk = ((mt >> 1) << 5) + (lg << 3) + reg + ((mt & 1) ? 4 : 0);
            vts[c0 + lc][mpk]      = f2b(acc[mt][0][reg] + bias0);
            vts[c0 + 16 + lc][mpk] = f2b(acc[mt][1][reg] + bias1);
          }
        }
      }
    }
  }
  __syncthreads();

  // ---- Phase E: attention for head h = w (swapped: St[m][n] = kn . qn) ----
  {
    const int h = w;
    const float sc = scaleg[h];
    f32x4 st[4][4];
#pragma unroll
    for (int mt = 0; mt < 4; ++mt)
#pragma unroll
      for (int nt = 0; nt < 4; ++nt) st[mt][nt] = fzero();
    {
      bf16x8 a[4], bq[4];
#pragma unroll
      for (int t4 = 0; t4 < 4; ++t4) {
        a[t4]  = ldfrag(&ks[t4 * 16 + lc][(h << 5) + (lg << 3)]);
        bq[t4] = ldfrag(&qs[t4 * 16 + lc][(h << 5) + (lg << 3)]);
      }
#pragma unroll
      for (int mt = 0; mt < 4; ++mt)
#pragma unroll
        for (int nt = 0; nt < 4; ++nt)
          st[mt][nt] = MFMA16(a[mt], bq[nt], st[mt][nt]);
    }
    // logits + column softmax (reduce over m = rows): in-lane 16 + shfl 16,32
    const float* bT = biasT + (h << 12);
#pragma unroll
    for (int nt = 0; nt < 4; ++nt) {
      int n = nt * 16 + lc;
      float mx = -3.0e38f;
#pragma unroll
      for (int mt = 0; mt < 4; ++mt)
#pragma unroll
        for (int reg = 0; reg < 4; ++reg) {
          int m = mt * 16 + (lg << 2) + reg;
          float val = st[mt][nt][reg] * sc + bT[(m << 6) + n] + ms[m][n];
          st[mt][nt][reg] = val;
          mx = fmaxf(mx, val);
        }
      mx = fmaxf(mx, __shfl_xor(mx, 16));
      mx = fmaxf(mx, __shfl_xor(mx, 32));
      float sm = 0.0f;
#pragma unroll
      for (int mt = 0; mt < 4; ++mt)
#pragma unroll
        for (int reg = 0; reg < 4; ++reg) {
          float e = __expf(st[mt][nt][reg] - mx);
          st[mt][nt][reg] = e;
          sm += e;
        }
      sm += __shfl_xor(sm, 16);
      sm += __shfl_xor(sm, 32);
      float inv = 1.0f / sm;
#pragma unroll
      for (int mt = 0; mt < 4; ++mt)
#pragma unroll
        for (int reg = 0; reg < 4; ++reg) st[mt][nt][reg] *= inv;
    }
    // PV: OT[d][n] = sum_m vT[d][m] * Pt[m][n]; P fragments are lane-local.
    f32x4 ot[2][4];
#pragma unroll
    for (int dmt = 0; dmt < 2; ++dmt)
#pragma unroll
      for (int nt = 0; nt < 4; ++nt) ot[dmt][nt] = fzero();
#pragma unroll
    for (int kt = 0; kt < 2; ++kt) {
      bf16x8 av[2];
#pragma unroll
      for (int dmt = 0; dmt < 2; ++dmt)
        av[dmt] = ldfrag(&vts[(h << 5) + dmt * 16 + lc][(kt << 5) + (lg << 3)]);
#pragma unroll
      for (int nt = 0; nt < 4; ++nt) {
        FragAB bp;
#pragma unroll
        for (int j = 0; j < 4; ++j) {
          bp.u[j]     = f2b(st[2 * kt][nt][j]);
          bp.u[4 + j] = f2b(st[2 * kt + 1][nt][j]);
        }
#pragma unroll
        for (int dmt = 0; dmt < 2; ++dmt)
          ot[dmt][nt] = MFMA16(av[dmt], bp.v, ot[dmt][nt]);
      }
    }
    // write attention output into xs (packed cols), att[n][h*32+d]
#pragma unroll
    for (int dmt = 0; dmt < 2; ++dmt)
#pragma unroll
      for (int nt = 0; nt < 4; ++nt)
#pragma unroll
        for (int reg = 0; reg < 4; ++reg) {
          int n = nt * 16 + lc;
          xs[n][(h << 5) + (lg << 3) + reg + (dmt ? 4 : 0)] = f2b(ot[dmt][nt][reg]);
        }
  }
  __syncthreads();

  // ---- Phase F: out = att @ pw^T + pb  (f32 store) ----
  {
    f32x4 acc[4][2];
#pragma unroll
    for (int mt = 0; mt < 4; ++mt)
#pragma unroll
      for (int nt = 0; nt < 2; ++nt) acc[mt][nt] = fzero();
#pragma unroll
    for (int kg = 0; kg < 8; ++kg) {
      bf16x8 a[4], bb[2];
#pragma unroll
      for (int mt = 0; mt < 4; ++mt)
        a[mt] = ldfrag(&xs[mt * 16 + lc][(kg << 5) + (lg << 3)]);
#pragma unroll
      for (int nt = 0; nt < 2; ++nt)
        bb[nt] = ldfrag(pwb + ((c0 + nt * 16 + lc) << 8) + (kg << 5) + (lg << 3));
#pragma unroll
      for (int mt = 0; mt < 4; ++mt)
#pragma unroll
        for (int nt = 0; nt < 2; ++nt)
          acc[mt][nt] = MFMA16(a[mt], bb[nt], acc[mt][nt]);
    }
    float bias0 = pb[c0 + lc], bias1 = pb[c0 + 16 + lc];
    float* op = outg + (size_t)b * 16384;
#pragma unroll
    for (int mt = 0; mt < 4; ++mt) {
#pragma unroll
      for (int reg = 0; reg < 4; ++reg) {
        int row = mt * 16 + (lg << 2) + reg;
        op[(row << 8) + c0 + lc]      = acc[mt][0][reg] + bias0;
        op[(row << 8) + c0 + 16 + lc] = acc[mt][1][reg] + bias1;
      }
    }
  }
}

// ---------------------------------------------------------------------------
extern "C" void kernel_launch(void* const* d_in, const int* in_sizes, int n_in,
                              void* d_out, int out_size, void* d_ws, size_t ws_size,
                              hipStream_t stream) {
  const float* x    = (const float*)d_in[0];
  const float* c    = (const float*)d_in[1];
  const float* mask = (const float*)d_in[2];
  const float* q_w  = (const float*)d_in[3];
  const float* q_b  = (const float*)d_in[4];
  const float* kv_w = (const float*)d_in[5];
  const float* kv_b = (const float*)d_in[6];
  const float* lsc  = (const float*)d_in[7];
  const float* rpb  = (const float*)d_in[8];
  const float* p_w  = (const float*)d_in[9];
  const float* p_b  = (const float*)d_in[10];

  char* ws = (char*)d_ws;
  ushort* qwb   = (ushort*)(ws);                       // 256*256*2  = 131072 B
  ushort* kvwb  = (ushort*)(ws + 131072);              // 512*256*2  = 262144 B
  ushort* pwb   = (ushort*)(ws + 131072 + 262144);     // 256*256*2  = 131072 B
  float*  biasT = (float*)(ws + 524288);               // 8*64*64*4  = 131072 B
  float*  scale = (float*)(ws + 524288 + 131072);      // 32 B

  prep_kernel<<<64, 256, 0, stream>>>(q_w, kv_w, p_w, rpb, lsc, qwb, kvwb, pwb, biasT, scale);
  wattn_fused<<<4096, 512, 0, stream>>>(x, c, mask, q_b, kv_b, p_b, qwb, kvwb, pwb,
                                        biasT, scale, (float*)d_out);
}